// Round 3
// baseline (1153.652 us; speedup 1.0000x reference)
//
#include <hip/hip_runtime.h>
#include <hip/hip_bf16.h>

// Problem: B=524288 rows, D=32, H=64, H2=32, E=8 experts, O=1.
// out[b] = sum_e sigmoid(relu(relu(x W1e + b1e) W2e + b2e) W3e + b3e) * probs[b,e]
// All inputs AND output fp32 (round-1 NaN proves fp32 inputs; round-2
// garbage-pattern proves fp32 output readback).

constexpr int DD = 32;   // input dim
constexpr int HH = 64;   // hidden 1
constexpr int KK = 32;   // hidden 2
constexpr int EE = 8;    // experts

// d_ws float layout:
//   W1T [8][64][32]  @ 0       (transposed: [e][h][d], contiguous in d)
//   W2T [8][32][64]  @ 16384   (transposed: [e][k][h], contiguous in h)
//   W3  [8][32]      @ 32768
//   b1  [8][64]      @ 33024
//   b2  [8][32]      @ 33536
//   b3  [8]          @ 33792   -> 33800 floats total (135 KB)

__global__ void cvt_weights(const float* __restrict__ W1,
                            const float* __restrict__ b1,
                            const float* __restrict__ W2,
                            const float* __restrict__ b2,
                            const float* __restrict__ W3,
                            const float* __restrict__ b3,
                            float* __restrict__ wf) {
    int i = blockIdx.x * blockDim.x + threadIdx.x;
    if (i < EE * DD * HH) {            // 16384: W1 [e][d][h] -> W1T [e][h][d]
        int e = i >> 11, rem = i & 2047, d = rem >> 6, h = rem & 63;
        wf[e * 2048 + h * 32 + d] = W1[i];
    }
    if (i < EE * HH * KK) {            // 16384: W2 [e][h][k] -> W2T [e][k][h]
        int e = i >> 11, rem = i & 2047, h = rem >> 5, k = rem & 31;
        wf[16384 + e * 2048 + k * 64 + h] = W2[i];
    }
    if (i < EE * KK) wf[32768 + i] = W3[i];   // 256 (O=1 so [e][k][0] flat)
    if (i < EE * HH) wf[33024 + i] = b1[i];   // 512
    if (i < EE * KK) wf[33536 + i] = b2[i];   // 256
    if (i < EE)      wf[33792 + i] = b3[i];   // 8
}

__global__ __launch_bounds__(256, 3)
void moe_main(const float* __restrict__ x,
              const float* __restrict__ probs,
              const float* __restrict__ wf,
              float* __restrict__ out, int nrows) {
    const int row = blockIdx.x * blockDim.x + threadIdx.x;
    if (row >= nrows) return;

    // Load x row: 32 fp32 = 128 B as 8x float4.
    float xr[DD];
    {
        const float4* xv = (const float4*)(x + (size_t)row * DD);
        #pragma unroll
        for (int v = 0; v < 8; ++v) {
            float4 q = xv[v];
            xr[v * 4 + 0] = q.x; xr[v * 4 + 1] = q.y;
            xr[v * 4 + 2] = q.z; xr[v * 4 + 3] = q.w;
        }
    }
    // Load probs row: 8 fp32 = 32 B as 2x float4.
    float pr[EE];
    {
        const float4* pv = (const float4*)(probs + (size_t)row * EE);
        float4 a = pv[0], b = pv[1];
        pr[0] = a.x; pr[1] = a.y; pr[2] = a.z; pr[3] = a.w;
        pr[4] = b.x; pr[5] = b.y; pr[6] = b.z; pr[7] = b.w;
    }

    const float* W1T = wf;
    const float* W2T = wf + 16384;
    const float* W3f = wf + 32768;
    const float* b1f = wf + 33024;
    const float* b2f = wf + 33536;
    const float* b3f = wf + 33792;

    float acc = 0.f;
    for (int e = 0; e < EE; ++e) {
        // Layer 1: h1[j] = relu(b1[j] + sum_i x[i] * W1T[e][j][i])
        float h1[HH];
        const float* w1 = W1T + e * 2048;
        #pragma unroll 8
        for (int j = 0; j < HH; ++j) {
            float t = b1f[e * HH + j];
            const float* wr = w1 + j * 32;
            #pragma unroll
            for (int i = 0; i < DD; ++i) t = fmaf(xr[i], wr[i], t);
            h1[j] = fmaxf(t, 0.f);
        }
        // Layers 2+3 fused: s = b3 + sum_k relu(b2[k] + sum_j h1[j]*W2T[e][k][j]) * W3[e][k]
        const float* w2 = W2T + e * 2048;
        const float* w3 = W3f + e * KK;
        float s = b3f[e];
        #pragma unroll 4
        for (int k = 0; k < KK; ++k) {
            float t = b2f[e * KK + k];
            const float* wr = w2 + k * 64;
            #pragma unroll
            for (int j = 0; j < HH; ++j) t = fmaf(h1[j], wr[j], t);
            s = fmaf(fmaxf(t, 0.f), w3[k], s);
        }
        float sig = 1.f / (1.f + __expf(-s));
        acc = fmaf(sig, pr[e], acc);
    }
    out[row] = acc;
}

extern "C" void kernel_launch(void* const* d_in, const int* in_sizes, int n_in,
                              void* d_out, int out_size, void* d_ws, size_t ws_size,
                              hipStream_t stream) {
    const float* x     = (const float*)d_in[0];
    const float* probs = (const float*)d_in[1];
    const float* W1    = (const float*)d_in[2];
    const float* b1    = (const float*)d_in[3];
    const float* W2    = (const float*)d_in[4];
    const float* b2    = (const float*)d_in[5];
    const float* W3    = (const float*)d_in[6];
    const float* b3    = (const float*)d_in[7];

    float* wf = (float*)d_ws;
    const int nrows = in_sizes[0] / DD;   // 524288

    hipLaunchKernelGGL(cvt_weights, dim3(64), dim3(256), 0, stream,
                       W1, b1, W2, b2, W3, b3, wf);
    hipLaunchKernelGGL(moe_main, dim3((nrows + 255) / 256), dim3(256), 0, stream,
                       x, probs, wf, (float*)d_out, nrows);
}

// Round 4
// 1123.504 us; speedup vs baseline: 1.0268x; 1.0268x over previous
//
#include <hip/hip_runtime.h>

// Problem: B=524288 rows, D=32, H=64, H2=32, E=8 experts, O=1.
// out[b] = sum_e sigmoid(relu(relu(x W1e + b1e) W2e + b2e) W3e + b3e) * probs[b,e]
// All inputs/outputs fp32. Round-3 lesson: h1[64] + launch_bounds(256,3)
// => VGPR cap 80 => 1.05 GB scratch spill traffic. This version keeps only
// a2[32] live (incremental layer-2 accumulation) and caps at 128 VGPRs.

constexpr int DD = 32;   // input dim
constexpr int HH = 64;   // hidden 1
constexpr int KK = 32;   // hidden 2
constexpr int EE = 8;    // experts

// Only W1 needs a transpose ([e][d][h] -> [e][h][d]); W2 [e][h][k] is already
// contiguous in k for the incremental update, W3/biases used as-is from d_in.
__global__ void cvt_w1(const float* __restrict__ W1, float* __restrict__ w1t) {
    int i = blockIdx.x * blockDim.x + threadIdx.x;
    if (i < EE * DD * HH) {            // 16384: W1 [e][d][h] -> w1t [e][h][d]
        int e = i >> 11, rem = i & 2047, d = rem >> 6, h = rem & 63;
        w1t[e * 2048 + h * 32 + d] = W1[i];
    }
}

__global__ __launch_bounds__(256, 4)   // 128-VGPR cap: ~95 needed, no spill
void moe_main(const float* __restrict__ x,
              const float* __restrict__ probs,
              const float* __restrict__ w1t,
              const float* __restrict__ W2,
              const float* __restrict__ W3,
              const float* __restrict__ b1,
              const float* __restrict__ b2,
              const float* __restrict__ b3,
              float* __restrict__ out, int nrows) {
    const int row = blockIdx.x * blockDim.x + threadIdx.x;
    if (row >= nrows) return;

    // x row: 32 fp32 = 128 B as 8x float4.
    float xr[DD];
    {
        const float4* xv = (const float4*)(x + (size_t)row * DD);
        #pragma unroll
        for (int v = 0; v < 8; ++v) {
            float4 q = xv[v];
            xr[v * 4 + 0] = q.x; xr[v * 4 + 1] = q.y;
            xr[v * 4 + 2] = q.z; xr[v * 4 + 3] = q.w;
        }
    }
    // probs row: 8 fp32 = 32 B as 2x float4.
    float pr[EE];
    {
        const float4* pv = (const float4*)(probs + (size_t)row * EE);
        float4 a = pv[0], b = pv[1];
        pr[0] = a.x; pr[1] = a.y; pr[2] = a.z; pr[3] = a.w;
        pr[4] = b.x; pr[5] = b.y; pr[6] = b.z; pr[7] = b.w;
    }

    float acc = 0.f;
    for (int e = 0; e < EE; ++e) {
        // Layer-2 accumulators, initialized with b2. Layer 1 is computed one
        // hidden unit at a time and immediately folded in -> no h1[] array.
        float a2[KK];
        const float* b2e = b2 + e * KK;
        #pragma unroll
        for (int k = 0; k < KK; ++k) a2[k] = b2e[k];

        const float* w1e = w1t + e * (HH * DD);
        const float* w2e = W2  + e * (HH * KK);
        const float* b1e = b1  + e * HH;

        #pragma unroll 2
        for (int j = 0; j < HH; ++j) {
            const float* wr = w1e + j * DD;      // wave-uniform -> s_load
            float t0 = 0.f, t1 = 0.f, t2 = 0.f, t3 = 0.f;  // 4-way ILP dot
            #pragma unroll
            for (int i = 0; i < DD; i += 4) {
                t0 = fmaf(xr[i + 0], wr[i + 0], t0);
                t1 = fmaf(xr[i + 1], wr[i + 1], t1);
                t2 = fmaf(xr[i + 2], wr[i + 2], t2);
                t3 = fmaf(xr[i + 3], wr[i + 3], t3);
            }
            float h = fmaxf((t0 + t1) + (t2 + t3) + b1e[j], 0.f);
            const float* w2r = w2e + j * KK;     // wave-uniform -> s_load
            #pragma unroll
            for (int k = 0; k < KK; ++k) a2[k] = fmaf(h, w2r[k], a2[k]);
        }

        const float* w3e = W3 + e * KK;          // W3[e][k][0] flat
        float s0 = 0.f, s1 = 0.f, s2 = 0.f, s3 = 0.f;
        #pragma unroll
        for (int k = 0; k < KK; k += 4) {
            s0 = fmaf(fmaxf(a2[k + 0], 0.f), w3e[k + 0], s0);
            s1 = fmaf(fmaxf(a2[k + 1], 0.f), w3e[k + 1], s1);
            s2 = fmaf(fmaxf(a2[k + 2], 0.f), w3e[k + 2], s2);
            s3 = fmaf(fmaxf(a2[k + 3], 0.f), w3e[k + 3], s3);
        }
        float s = (s0 + s1) + (s2 + s3) + b3[e];
        float sig = 1.f / (1.f + __expf(-s));
        acc = fmaf(sig, pr[e], acc);
    }
    out[row] = acc;
}

extern "C" void kernel_launch(void* const* d_in, const int* in_sizes, int n_in,
                              void* d_out, int out_size, void* d_ws, size_t ws_size,
                              hipStream_t stream) {
    const float* x     = (const float*)d_in[0];
    const float* probs = (const float*)d_in[1];
    const float* W1    = (const float*)d_in[2];
    const float* b1    = (const float*)d_in[3];
    const float* W2    = (const float*)d_in[4];
    const float* b2    = (const float*)d_in[5];
    const float* W3    = (const float*)d_in[6];
    const float* b3    = (const float*)d_in[7];

    float* w1t = (float*)d_ws;                 // 16384 floats = 64 KB
    const int nrows = in_sizes[0] / DD;        // 524288

    hipLaunchKernelGGL(cvt_w1, dim3(64), dim3(256), 0, stream, W1, w1t);
    hipLaunchKernelGGL(moe_main, dim3((nrows + 255) / 256), dim3(256), 0, stream,
                       x, probs, w1t, W2, W3, b1, b2, b3, (float*)d_out, nrows);
}

// Round 5
// 191.980 us; speedup vs baseline: 6.0092x; 5.8522x over previous
//
#include <hip/hip_runtime.h>

// EnhancedMoEModel: B=524288, D=32, H=64, H2=32, E=8, O=1. fp32 in/out.
// out[b] = sum_e sigmoid(relu(relu(x W1e) W2e + b2) W3e + b3) * probs[b,e]
//
// R5 design: expert-stationary MFMA. Wave w of each 8-wave block owns expert w,
// holding pre-packed weight fragments in registers. Layers computed transposed
// (M = hidden dim, N = 16 batch rows) so layer1's C-fragment IS layer2's
// B-fragment for 16x16x16 MFMA (C/D layout col=lane&15,row=4q+r == B layout
// n=lane&15,k=4q+r). No LDS round-trip, no cross-lane shuffles in the chain.
// R4 lesson: compiler squeezed VGPRs to 64 and spilled 600 MB; pin with
// amdgpu_waves_per_eu(4,4) (max=4 forbids the 8-wave squeeze).

constexpr int RB = 512;   // rows per block; 8 waves x 32 iters of 16 rows

typedef __attribute__((ext_vector_type(4))) short bf16x4;
typedef __attribute__((ext_vector_type(8))) short bf16x8;
typedef __attribute__((ext_vector_type(4))) float f32x4;

// d_ws layout (shorts unless noted):
//   w1p [e][mt=4][lane=64][j=8] bf16   @ 0       (16384 shorts, 32 KB)
//   w2p [e][mt2=2][kb=4][lane][j=4]    @ 16384   (16384 shorts, 32 KB)
//   b1p [e][lane][16] f32              @ byte 65536  (8192 f32, 32 KB)
//   b2p [e][lane][8]  f32              @ +32768      (4096 f32, 16 KB)
//   w3p [e][lane][8]  f32              @ +16384      (4096 f32, 16 KB)

__device__ __forceinline__ short f2bf_rne(float f) {
    unsigned u = __float_as_uint(f);
    unsigned r = (u + 0x7fffu + ((u >> 16) & 1u)) >> 16;
    return (short)r;
}

// pack two fp32 -> dword of 2 bf16 (round-half-up: +0x8000 then take hi16).
__device__ __forceinline__ unsigned pk2(float lo, float hi) {
    unsigned ulo = __float_as_uint(lo) + 0x8000u;
    unsigned uhi = __float_as_uint(hi) + 0x8000u;
    // v_perm {S0=uhi, S1=ulo}: byte sel 0..3 = ulo, 4..7 = uhi
    return __builtin_amdgcn_perm(uhi, ulo, 0x07060302u);
}

__device__ __forceinline__ f32x4 mfma16(bf16x4 a, bf16x4 b, f32x4 c) {
#if __has_builtin(__builtin_amdgcn_mfma_f32_16x16x16bf16_1k)
    return __builtin_amdgcn_mfma_f32_16x16x16bf16_1k(a, b, c, 0, 0, 0);
#elif __has_builtin(__builtin_amdgcn_mfma_f32_16x16x16_bf16)
    return __builtin_amdgcn_mfma_f32_16x16x16_bf16(a, b, c, 0, 0, 0);
#else
    asm volatile("v_mfma_f32_16x16x16_bf16 %0, %1, %2, %0\n\t"
                 "s_nop 7\n\ts_nop 3"
                 : "+v"(c) : "v"(a), "v"(b));
    return c;
#endif
}

__global__ void cvt_pack(const float* __restrict__ W1, const float* __restrict__ b1,
                         const float* __restrict__ W2, const float* __restrict__ b2,
                         const float* __restrict__ W3, short* __restrict__ ws) {
    int i = blockIdx.x * blockDim.x + threadIdx.x;   // 16384 threads
    short* w1p = ws;
    short* w2p = ws + 16384;
    float* b1p = (float*)(ws + 32768);
    float* b2p = b1p + 8192;
    float* w3p = b2p + 4096;
    if (i < 16384) {
        {   // w1p[e][mt][lane][j] = W1[e][d=8q+j][h=16mt+n]
            int j = i & 7, lane = (i >> 3) & 63, mt = (i >> 9) & 3, e = i >> 11;
            int n = lane & 15, q = lane >> 4;
            int d = q * 8 + j, h = 16 * mt + n;
            w1p[i] = f2bf_rne(W1[(e * 32 + d) * 64 + h]);
        }
        {   // w2p[e][mt2][kb][lane][j] = W2[e][h=16kb+4q+j][h2=16mt2+n]
            int j = i & 3, lane = (i >> 2) & 63, kb = (i >> 8) & 3,
                mt2 = (i >> 10) & 1, e = i >> 11;
            int n = lane & 15, q = lane >> 4;
            int h = 16 * kb + 4 * q + j, h2 = 16 * mt2 + n;
            w2p[i] = f2bf_rne(W2[(e * 64 + h) * 32 + h2]);
        }
    }
    if (i < 8192) {   // b1p[e][lane][mt*4+r] = b1[e][16mt+4q+r]
        int idx = i & 15, lane = (i >> 4) & 63, e = i >> 10;
        int q = lane >> 4, h = 16 * (idx >> 2) + 4 * q + (idx & 3);
        b1p[i] = b1[e * 64 + h];
    }
    if (i < 4096) {   // b2p/w3p[e][lane][mt2*4+r] = .[e][16mt2+4q+r]
        int idx = i & 7, lane = (i >> 3) & 63, e = i >> 9;
        int q = lane >> 4, h2 = 16 * (idx >> 2) + 4 * q + (idx & 3);
        b2p[i] = b2[e * 32 + h2];
        w3p[i] = W3[e * 32 + h2];
    }
}

__attribute__((amdgpu_flat_work_group_size(512, 512), amdgpu_waves_per_eu(4, 4)))
__global__ void moe_main(const float* __restrict__ x,
                         const float* __restrict__ probs,
                         const short* __restrict__ ws,
                         const float* __restrict__ b3,
                         float* __restrict__ out) {
    __shared__ float sbuf[8][RB];
    const int tid = threadIdx.x;
    const int w = tid >> 6, lane = tid & 63, n = lane & 15, q = lane >> 4;

    const short* w1p = ws;
    const short* w2p = ws + 16384;
    const float* b1p = (const float*)(ws + 32768);
    const float* b2p = b1p + 8192;
    const float* w3p = b2p + 4096;

    // Per-expert weight fragments -> registers (once per block).
    bf16x8 w1f[4];
    #pragma unroll
    for (int mt = 0; mt < 4; ++mt)
        w1f[mt] = *(const bf16x8*)(w1p + ((w * 4 + mt) * 64 + lane) * 8);
    bf16x4 w2f[2][4];
    #pragma unroll
    for (int mt2 = 0; mt2 < 2; ++mt2)
        #pragma unroll
        for (int kb = 0; kb < 4; ++kb)
            w2f[mt2][kb] = *(const bf16x4*)(w2p + (((w * 2 + mt2) * 4 + kb) * 64 + lane) * 4);
    f32x4 b1f[4];
    #pragma unroll
    for (int mt = 0; mt < 4; ++mt)
        b1f[mt] = *(const f32x4*)(b1p + (w * 64 + lane) * 16 + mt * 4);
    f32x4 b2f[2], w3f[2];
    #pragma unroll
    for (int mt2 = 0; mt2 < 2; ++mt2) {
        b2f[mt2] = *(const f32x4*)(b2p + (w * 64 + lane) * 8 + mt2 * 4);
        w3f[mt2] = *(const f32x4*)(w3p + (w * 64 + lane) * 8 + mt2 * 4);
    }
    const float b3v = b3[w];
    const size_t rowbase = (size_t)blockIdx.x * RB;

    for (int it = 0; it < RB / 16; ++it) {
        const size_t row = rowbase + it * 16 + n;
        // X^T B-fragment: lane holds x[row=n][d=8q..8q+7], fp32->bf16.
        const float* xp = x + row * 32 + q * 8;
        f32x4 xa = *(const f32x4*)xp;
        f32x4 xb = *(const f32x4*)(xp + 4);
        union { bf16x8 v; unsigned u[4]; } xf;
        xf.u[0] = pk2(xa.x, xa.y); xf.u[1] = pk2(xa.z, xa.w);
        xf.u[2] = pk2(xb.x, xb.y); xf.u[3] = pk2(xb.z, xb.w);

        // Layer 1: H1^T[16mt+4q+r][row], 4x mfma 16x16x32, acc init = b1.
        f32x4 c1[4];
        #pragma unroll
        for (int mt = 0; mt < 4; ++mt)
            c1[mt] = __builtin_amdgcn_mfma_f32_16x16x32_bf16(w1f[mt], xf.v, b1f[mt], 0, 0, 0);

        // relu + pack: C1 frag == B-frag (k=4q+r) of 16x16x16 for layer 2.
        bf16x4 p[4];
        #pragma unroll
        for (int mt = 0; mt < 4; ++mt) {
            union { bf16x4 v; unsigned u[2]; } t;
            t.u[0] = pk2(fmaxf(c1[mt].x, 0.f), fmaxf(c1[mt].y, 0.f));
            t.u[1] = pk2(fmaxf(c1[mt].z, 0.f), fmaxf(c1[mt].w, 0.f));
            p[mt] = t.v;
        }

        // Layer 2: H2^T[16mt2+4q+r][row], 2 M-tiles x 4 K-blocks, acc init = b2.
        f32x4 c2[2];
        #pragma unroll
        for (int mt2 = 0; mt2 < 2; ++mt2) {
            f32x4 a = b2f[mt2];
            #pragma unroll
            for (int kb = 0; kb < 4; ++kb)
                a = mfma16(w2f[mt2][kb], p[kb], a);
            c2[mt2] = a;
        }

        // Layer 3: s[row] = sum_h2 relu(H2) * w3. Lane partial over its 8 h2,
        // then quad-reduce (lanes n, n+16, n+32, n+48).
        float pl = 0.f;
        #pragma unroll
        for (int mt2 = 0; mt2 < 2; ++mt2) {
            pl = fmaf(fmaxf(c2[mt2].x, 0.f), w3f[mt2].x, pl);
            pl = fmaf(fmaxf(c2[mt2].y, 0.f), w3f[mt2].y, pl);
            pl = fmaf(fmaxf(c2[mt2].z, 0.f), w3f[mt2].z, pl);
            pl = fmaf(fmaxf(c2[mt2].w, 0.f), w3f[mt2].w, pl);
        }
        pl += __shfl_xor(pl, 16);
        pl += __shfl_xor(pl, 32);
        const float s = pl + b3v;
        const float sig = 1.f / (1.f + __expf(-s));
        const float pb = probs[row * 8 + w];
        if (q == 0) sbuf[w][it * 16 + n] = sig * pb;
    }

    __syncthreads();
    // Combine experts: thread t sums sbuf[0..7][t]; coalesced 2 KB store.
    float r = 0.f;
    #pragma unroll
    for (int e = 0; e < 8; ++e) r += sbuf[e][tid];
    out[rowbase + tid] = r;
}

extern "C" void kernel_launch(void* const* d_in, const int* in_sizes, int n_in,
                              void* d_out, int out_size, void* d_ws, size_t ws_size,
                              hipStream_t stream) {
    const float* x     = (const float*)d_in[0];
    const float* probs = (const float*)d_in[1];
    const float* W1    = (const float*)d_in[2];
    const float* b1    = (const float*)d_in[3];
    const float* W2    = (const float*)d_in[4];
    const float* b2    = (const float*)d_in[5];
    const float* W3    = (const float*)d_in[6];
    const float* b3    = (const float*)d_in[7];

    short* ws = (short*)d_ws;
    const int nrows = in_sizes[0] / 32;          // 524288

    hipLaunchKernelGGL(cvt_pack, dim3(64), dim3(256), 0, stream,
                       W1, b1, W2, b2, W3, ws);
    hipLaunchKernelGGL(moe_main, dim3(nrows / RB), dim3(512), 0, stream,
                       x, probs, ws, b3, (float*)d_out);
}